// Round 21
// baseline (988.233 us; speedup 1.0000x reference)
//
#include <hip/hip_runtime.h>
#include <math.h>

#define H 43
#define HP 64                     // fp16 row pad -> 128B
#define HR 44                     // f32 h row stride
#define NC 176                    // B cols: 44 f-groups x 4 gates
#define KD 128                    // GEMM K: agg(64) | h(64)
#define NN 100000
#define NE 1600000
#define NG 2048
#define FFD 392
#define NLB 138
#define NXCD 8
#define SHARD 12544               // 128 buckets of 98 nodes
#define GRU_GRID (NXCD * 98)
#define GA_BLOCKS 2048            // persistent gather: 8 shards x 256 blocks
#define NSB 1024                  // sub-buckets
#define RNG 98                    // dst-nodes per sub-bucket
#define SCAP 2048                 // per-sub-bucket edge capacity (mean 1562)
#define PB 256                    // partition grid
#define PCHUNK ((NE + PB - 1) / PB) // 6250

typedef _Float16 half8 __attribute__((ext_vector_type(8)));
typedef float f32x4 __attribute__((ext_vector_type(4)));

// ---------- partition: edges -> 1024 sub-buckets, packed (src<<7 | d_local) ----------
__global__ void part1024(const int* __restrict__ src, const int* __restrict__ dst,
                         int* __restrict__ scnt, int* __restrict__ ebuf) {
    __shared__ int cnt[NSB];
    __shared__ int base[NSB];
    int e0 = blockIdx.x * PCHUNK, e1 = min(NE, e0 + PCHUNK);
    for (int i = threadIdx.x; i < NSB; i += 256) cnt[i] = 0;
    __syncthreads();
    for (int e = e0 + threadIdx.x; e < e1; e += 256) {
        atomicAdd(&cnt[dst[e] / RNG], 1);
    }
    __syncthreads();
    for (int i = threadIdx.x; i < NSB; i += 256) {
        base[i] = cnt[i] ? atomicAdd(&scnt[i], cnt[i]) : 0;
        cnt[i] = 0;
    }
    __syncthreads();
    for (int e = e0 + threadIdx.x; e < e1; e += 256) {
        int d = dst[e];
        int s = d / RNG;
        int dl = d - s * RNG;
        int off = atomicAdd(&cnt[s], 1);
        int slot = base[s] + off;
        if (slot < SCAP) ebuf[(size_t)s * SCAP + slot] = (src[e] << 7) | dl;
    }
}

// ---------- per-bucket LDS counting sort -> coalesced esorted + rowb/rowe ----------
__global__ __launch_bounds__(256) void sort_sb(const int* __restrict__ ebuf,
                                               const int* __restrict__ scnt,
                                               int* __restrict__ esorted,
                                               int* __restrict__ rowb,
                                               int* __restrict__ rowe) {
    __shared__ int cnt[RNG + 1];
    __shared__ int lpre[RNG + 1];
    __shared__ int inb[SCAP];
    __shared__ int outb[SCAP];
    int b = blockIdx.x;
    int n = min(scnt[b], SCAP);
    const int* buf = ebuf + (size_t)b * SCAP;
    for (int i = threadIdx.x; i < RNG + 1; i += 256) cnt[i] = 0;
    __syncthreads();
    for (int i = threadIdx.x; i < n; i += 256) {
        int p = buf[i];
        inb[i] = p;
        atomicAdd(&cnt[p & 127], 1);
    }
    __syncthreads();
    if (threadIdx.x == 0) {
        int run = 0;
        for (int d = 0; d <= RNG; ++d) { lpre[d] = run; run += cnt[d]; }
    }
    __syncthreads();
    for (int i = threadIdx.x; i < RNG + 1; i += 256) cnt[i] = 0;
    __syncthreads();
    for (int i = threadIdx.x; i < n; i += 256) {
        int p = inb[i];
        int d = p & 127;
        int slot = lpre[d] + atomicAdd(&cnt[d], 1);
        outb[slot] = p >> 7;             // store src only
    }
    __syncthreads();
    for (int i = threadIdx.x; i < n; i += 256)
        esorted[(size_t)b * SCAP + i] = outb[i];   // coalesced
    for (int d = threadIdx.x; d < RNG; d += 256) {
        int node = b * RNG + d;
        if (node < NN) {
            rowb[node] = b * SCAP + lpre[d];
            rowe[node] = b * SCAP + lpre[d + 1];
        }
    }
}

// ---------- Bp: per-layer fused GRU weight matrix, fragment-packed fp16 ----------
__global__ void bp_build(const float* __restrict__ W, const float* __restrict__ W_ih,
                         const float* __restrict__ W_hh, const float* __restrict__ b_ih,
                         const float* __restrict__ b_hh, _Float16* __restrict__ Bp) {
    int t = blockIdx.x * blockDim.x + threadIdx.x;
    if (t >= 5 * KD * NC) return;
    int l = t / (KD * NC);
    int rem = t % (KD * NC);
    int k = rem / NC, c = rem % NC;
    int f = c >> 2, gate = c & 3;
    float v = 0.f;
    if (f < H) {
        if (k < H) {
            if (gate < 3) {
                int col = gate * H + f;
                float acc = 0.f;
#pragma unroll
                for (int c2 = 0; c2 < H; ++c2)
                    acc += W[((size_t)l * H + k) * H + c2] * W_ih[col * H + c2];
                v = acc;
            }
        } else if (k == H) {
            v = (gate == 0) ? b_ih[f] + b_hh[f]
              : (gate == 1) ? b_ih[H + f] + b_hh[H + f]
              : (gate == 2) ? b_ih[2 * H + f]
                            : b_hh[2 * H + f];
        } else if (k >= 64) {
            int k2 = k - 64;
            if (k2 < H) {
                if (gate == 0)      v = W_hh[f * H + k2];
                else if (gate == 1) v = W_hh[(H + f) * H + k2];
                else if (gate == 3) v = W_hh[(2 * H + f) * H + k2];
            }
        }
    }
    int nt = c >> 4, cl = c & 15;
    int kk = k >> 5, r = k & 31;
    int lane = ((r >> 3) << 4) | cl, j = r & 7;
    Bp[(((size_t)l * 11 + nt) * 4 + kk) * 512 + lane * 8 + j] = (_Float16)v;
}

// ---------- generic transpose ----------
__global__ void tr_mat(const float* __restrict__ A, float* __restrict__ At, int R, int C) {
    int t = blockIdx.x * blockDim.x + threadIdx.x;
    if (t >= R * C) return;
    int i = t / C, j = t % C;
    At[(size_t)j * R + i] = A[t];
}

// ---------- seed hh (fp16 rows) and h32 (f32 rows) from x ----------
__global__ void seed_hh(const float* __restrict__ x, _Float16* __restrict__ hh) {
    int t = blockIdx.x * blockDim.x + threadIdx.x;
    if (t >= NN * HP) return;
    int n = t >> 6, f = t & (HP - 1);
    hh[t] = (f < H) ? (_Float16)x[n * H + f] : (_Float16)0.f;
}

__global__ void seed_h32(const float* __restrict__ x, float* __restrict__ h32) {
    int t = blockIdx.x * blockDim.x + threadIdx.x;
    if (t >= NN * HR) return;
    int n = t / HR, f = t % HR;
    h32[t] = (f < H) ? x[n * H + f] : 0.f;
}

// ---------- gather (persistent): each wave loops over nodes of its shard ----------
__global__ __launch_bounds__(256) void gather_t(const _Float16* __restrict__ hh,
                                                const int* __restrict__ rowb,
                                                const int* __restrict__ rowe,
                                                const int* __restrict__ esorted,
                                                _Float16* __restrict__ aggF16) {
    int g = blockIdx.x & (NXCD - 1);
    int i = blockIdx.x >> 3;               // 0..255
    int w = threadIdx.x >> 6;
    int lane = threadIdx.x & 63;
    int fc = (lane < H) ? lane : 0;

    for (int loc = i * 4 + w; loc < SHARD; loc += 1024) {
        int wid = g * SHARD + loc;
        if (wid >= NN) break;              // only the last shard has a tail
        int beg = rowb[wid], end = rowe[wid];
        float acc = 0.f;
        for (int base = beg; base < end; base += 64) {
            int cnt = min(64, end - base);
            int idx = (base + lane < end) ? esorted[base + lane] : 0;
            int r = 0;
            for (; r + 16 <= cnt; r += 16) {
                int ss[16];
                float vv[16];
#pragma unroll
                for (int q = 0; q < 16; ++q) ss[q] = __shfl(idx, r + q);
#pragma unroll
                for (int q = 0; q < 16; ++q) vv[q] = (float)hh[(size_t)ss[q] * HP + fc];
                float s01 = (vv[0] + vv[1]) + (vv[2] + vv[3]);
                float s23 = (vv[4] + vv[5]) + (vv[6] + vv[7]);
                float s45 = (vv[8] + vv[9]) + (vv[10] + vv[11]);
                float s67 = (vv[12] + vv[13]) + (vv[14] + vv[15]);
                acc += (s01 + s23) + (s45 + s67);
            }
            if (r + 8 <= cnt) {
                int s0 = __shfl(idx, r + 0), s1 = __shfl(idx, r + 1);
                int s2 = __shfl(idx, r + 2), s3 = __shfl(idx, r + 3);
                int s4 = __shfl(idx, r + 4), s5 = __shfl(idx, r + 5);
                int s6 = __shfl(idx, r + 6), s7 = __shfl(idx, r + 7);
                float v0 = (float)hh[(size_t)s0 * HP + fc];
                float v1 = (float)hh[(size_t)s1 * HP + fc];
                float v2 = (float)hh[(size_t)s2 * HP + fc];
                float v3 = (float)hh[(size_t)s3 * HP + fc];
                float v4 = (float)hh[(size_t)s4 * HP + fc];
                float v5 = (float)hh[(size_t)s5 * HP + fc];
                float v6 = (float)hh[(size_t)s6 * HP + fc];
                float v7 = (float)hh[(size_t)s7 * HP + fc];
                acc += ((v0 + v1) + (v2 + v3)) + ((v4 + v5) + (v6 + v7));
                r += 8;
            }
            if (r + 4 <= cnt) {
                int s0 = __shfl(idx, r + 0), s1 = __shfl(idx, r + 1);
                int s2 = __shfl(idx, r + 2), s3 = __shfl(idx, r + 3);
                float v0 = (float)hh[(size_t)s0 * HP + fc];
                float v1 = (float)hh[(size_t)s1 * HP + fc];
                float v2 = (float)hh[(size_t)s2 * HP + fc];
                float v3 = (float)hh[(size_t)s3 * HP + fc];
                acc += (v0 + v1) + (v2 + v3);
                r += 4;
            }
            for (; r < cnt; ++r) {
                int s = __shfl(idx, r);
                acc += (float)hh[(size_t)s * HP + fc];
            }
        }
        _Float16 ov = (lane < H) ? (_Float16)acc : (lane == H) ? (_Float16)1.f : (_Float16)0.f;
        aggF16[(size_t)wid * HP + lane] = ov;
    }
}

// ---------- GRU via MFMA, barrier-free (double-buffered hh) ----------
__global__ __launch_bounds__(256) void gru_mfma(const _Float16* __restrict__ aggF16,
                                                const _Float16* __restrict__ hh_in,
                                                _Float16* __restrict__ hh_out,
                                                float* __restrict__ h32,
                                                const _Float16* __restrict__ Bp_l) {
    int g = blockIdx.x & (NXCD - 1);
    int blk = blockIdx.x >> 3;
    int lane = threadIdx.x & 63;
    int w = __builtin_amdgcn_readfirstlane(threadIdx.x >> 6);
    int m = lane & 15, kb = lane >> 4;
    int gate = lane & 3;
    int qbase = lane & ~3;

    half8 bf[3][4];
#pragma unroll
    for (int s = 0; s < 3; ++s) {
        int nt = w + s * 4;
        if (nt < 11) {
#pragma unroll
            for (int kk = 0; kk < 4; ++kk)
                bf[s][kk] = *(const half8*)(Bp_l + (((size_t)nt * 4 + kk) * 64 + lane) * 8);
        }
    }

    for (int it = 0; it < 8; ++it) {
        int node0 = g * SHARD + (blk * 8 + it) * 16;
        int ncl = min(node0 + m, NN - 1);
        half8 a0 = *(const half8*)(aggF16 + (size_t)ncl * HP + kb * 8);
        half8 a1 = *(const half8*)(aggF16 + (size_t)ncl * HP + 32 + kb * 8);
        half8 a2 = *(const half8*)(hh_in + (size_t)ncl * HP + kb * 8);
        half8 a3 = *(const half8*)(hh_in + (size_t)ncl * HP + 32 + kb * 8);
#pragma unroll
        for (int s = 0; s < 3; ++s) {
            int nt = w + s * 4;
            if (nt >= 11) continue;
            f32x4 acc = {0.f, 0.f, 0.f, 0.f};
            acc = __builtin_amdgcn_mfma_f32_16x16x32_f16(a0, bf[s][0], acc, 0, 0, 0);
            acc = __builtin_amdgcn_mfma_f32_16x16x32_f16(a1, bf[s][1], acc, 0, 0, 0);
            acc = __builtin_amdgcn_mfma_f32_16x16x32_f16(a2, bf[s][2], acc, 0, 0, 0);
            acc = __builtin_amdgcn_mfma_f32_16x16x32_f16(a3, bf[s][3], acc, 0, 0, 0);
            int f = nt * 4 + ((lane & 15) >> 2);
            float y0 = 0.f, y1 = 0.f, y2 = 0.f, y3 = 0.f;
#pragma unroll
            for (int j = 0; j < 4; ++j) {
                float v = acc[j];
                float x0 = __shfl(v, qbase + 0);
                float x1 = __shfl(v, qbase + 1);
                float x2 = __shfl(v, qbase + 2);
                float x3 = __shfl(v, qbase + 3);
                if (j == gate) { y0 = x0; y1 = x1; y2 = x2; y3 = x3; }
            }
            int node = node0 + (lane >> 4) * 4 + gate;
            if (f < H && node < NN) {
                float r = 1.f / (1.f + __expf(-y0));
                float z = 1.f / (1.f + __expf(-y1));
                float na = y2 + r * y3;
                float e2 = __expf(2.f * na);
                float nv = 1.f - 2.f / (e2 + 1.f);
                float hp = h32[(size_t)node * HR + f];
                float hnew = (1.f - z) * nv + z * hp;
                h32[(size_t)node * HR + f] = hnew;
                hh_out[(size_t)node * HP + f] = (_Float16)hnew;
            }
        }
    }
    for (int i = threadIdx.x; i < 128 * (HP - H); i += 256) {
        int nl = i / (HP - H), f = H + i % (HP - H);
        int node = g * SHARD + blk * 128 + nl;
        if (node < NN) hh_out[(size_t)node * HP + f] = (_Float16)0.f;
    }
}

// ---------- pool over sorted batch ----------
__global__ void pool_r(const float* __restrict__ h32, const int* __restrict__ batch,
                       float* __restrict__ gout) {
    int wid = (blockIdx.x * blockDim.x + threadIdx.x) >> 6;
    int lane = threadIdx.x & 63;
    if (wid >= NG) return;
    int lo = 0, hi = NN;
    while (lo < hi) { int mid = (lo + hi) >> 1; if (batch[mid] < wid) lo = mid + 1; else hi = mid; }
    int beg = lo;
    lo = beg; hi = NN;
    while (lo < hi) { int mid = (lo + hi) >> 1; if (batch[mid] < wid + 1) lo = mid + 1; else hi = mid; }
    int end = lo;
    if (lane < H) {
        float acc = 0.f;
        for (int n = beg; n < end; ++n) acc += h32[(size_t)n * HR + lane];
        gout[wid * H + lane] = acc;
    }
}

// ---------- dense with transposed weights (proven: unroll 4, RB=8); 1-wave blocks ----------
template <int K, int ACT, int RB>
__global__ __launch_bounds__(64) void dense_t(const float* __restrict__ in,
                                              const float* __restrict__ Wt,
                                              const float* __restrict__ b,
                                              float* __restrict__ out,
                                              int rows, int cols) {
    int t = blockIdx.x * blockDim.x + threadIdx.x;
    int ngroups = rows / RB;
    if (t >= ngroups * cols) return;
    int c = t % cols;
    int r0 = (t / cols) * RB;
    float acc[RB];
#pragma unroll
    for (int r = 0; r < RB; ++r) acc[r] = b[c];
#pragma unroll 4
    for (int k = 0; k < K; ++k) {
        float w = Wt[(size_t)k * cols + c];
#pragma unroll
        for (int r = 0; r < RB; ++r) acc[r] += in[(r0 + r) * K + k] * w;
    }
#pragma unroll
    for (int r = 0; r < RB; ++r) {
        float v = acc[r];
        v = (ACT == 0) ? fmaxf(v, 0.f) : 1.f / (1.f + expf(-v));
        out[(r0 + r) * cols + c] = v;
    }
}

static inline size_t rnd256(size_t x) { return (x + 255) & ~(size_t)255; }

extern "C" void kernel_launch(void* const* d_in, const int* in_sizes, int n_in,
                              void* d_out, int out_size, void* d_ws, size_t ws_size,
                              hipStream_t stream) {
    const float* x     = (const float*)d_in[0];
    const int*   ei    = (const int*)d_in[1];
    const int*   batch = (const int*)d_in[2];
    const float* W     = (const float*)d_in[3];
    const float* W_ih  = (const float*)d_in[4];
    const float* W_hh  = (const float*)d_in[5];
    const float* b_ih  = (const float*)d_in[6];
    const float* b_hh  = (const float*)d_in[7];
    const float* W1    = (const float*)d_in[8];
    const float* b1    = (const float*)d_in[9];
    const float* W2    = (const float*)d_in[10];
    const float* b2    = (const float*)d_in[11];
    const float* W3    = (const float*)d_in[12];
    const float* b3    = (const float*)d_in[13];
    const float* Wp    = (const float*)d_in[14];
    const float* bp    = (const float*)d_in[15];
    float* out = (float*)d_out;

    const int* src = ei;
    const int* dst = ei + NE;

    char* ws = (char*)d_ws;
    _Float16* aggF16 = (_Float16*)ws; ws += rnd256((size_t)NN * HP * sizeof(_Float16));
    _Float16* hha    = (_Float16*)ws; ws += rnd256((size_t)NN * HP * sizeof(_Float16));
    _Float16* hhb    = (_Float16*)ws; ws += rnd256((size_t)NN * HP * sizeof(_Float16));
    float*    h32    = (float*)ws;    ws += rnd256((size_t)NN * HR * sizeof(float));
    int*   ebuf  = (int*)ws;   ws += rnd256((size_t)NSB * SCAP * sizeof(int));
    int*   esrt  = (int*)ws;   ws += rnd256((size_t)NSB * SCAP * sizeof(int));
    int*   scnt  = (int*)ws;   ws += rnd256((size_t)NSB * sizeof(int));
    int*   rowb  = (int*)ws;   ws += rnd256((size_t)NN * sizeof(int));
    int*   rowe  = (int*)ws;   ws += rnd256((size_t)NN * sizeof(int));
    _Float16* Bp = (_Float16*)ws; ws += rnd256((size_t)5 * 11 * 4 * 512 * sizeof(_Float16));
    float* gbuf  = (float*)ws; ws += rnd256((size_t)NG * H * sizeof(float));
    float* f1    = (float*)ws; ws += rnd256((size_t)NG * FFD * sizeof(float));
    float* f2    = (float*)ws; ws += rnd256((size_t)NG * FFD * sizeof(float));
    float* f3    = (float*)ws; ws += rnd256((size_t)NG * FFD * sizeof(float));
    float* W1t   = (float*)ws; ws += rnd256((size_t)H * FFD * sizeof(float));
    float* W2t   = (float*)ws; ws += rnd256((size_t)FFD * FFD * sizeof(float));
    float* W3t   = (float*)ws; ws += rnd256((size_t)FFD * FFD * sizeof(float));
    float* Wpt   = (float*)ws; ws += rnd256((size_t)FFD * NLB * sizeof(float));

    const int blk = 256;

    // ---- edge prep: bin -> per-bucket LDS sort ----
    hipMemsetAsync(scnt, 0, (size_t)NSB * sizeof(int), stream);
    part1024<<<PB, blk, 0, stream>>>(src, dst, scnt, ebuf);
    sort_sb<<<NSB, blk, 0, stream>>>(ebuf, scnt, esrt, rowb, rowe);

    // ---- weight prep + seed ----
    bp_build<<<(5 * KD * NC + blk - 1) / blk, blk, 0, stream>>>(W, W_ih, W_hh, b_ih, b_hh, Bp);
    seed_hh<<<(NN * HP + blk - 1) / blk, blk, 0, stream>>>(x, hha);
    seed_h32<<<(NN * HR + blk - 1) / blk, blk, 0, stream>>>(x, h32);
    tr_mat<<<(FFD * H + blk - 1) / blk, blk, 0, stream>>>(W1, W1t, FFD, H);
    tr_mat<<<(FFD * FFD + blk - 1) / blk, blk, 0, stream>>>(W2, W2t, FFD, FFD);
    tr_mat<<<(FFD * FFD + blk - 1) / blk, blk, 0, stream>>>(W3, W3t, FFD, FFD);
    tr_mat<<<(NLB * FFD + blk - 1) / blk, blk, 0, stream>>>(Wp, Wpt, NLB, FFD);

    // ---- 5 GGC layers (hh ping-pong) ----
    _Float16* hcur = hha;
    _Float16* hnxt = hhb;
    for (int l = 0; l < 5; ++l) {
        gather_t<<<GA_BLOCKS, blk, 0, stream>>>(hcur, rowb, rowe, esrt, aggF16);
        gru_mfma<<<GRU_GRID, blk, 0, stream>>>(aggF16, hcur, hnxt, h32,
                                               Bp + (size_t)l * 11 * 4 * 512);
        _Float16* t = hcur; hcur = hnxt; hnxt = t;
    }

    // ---- pool ----
    pool_r<<<(NG * 64 + blk - 1) / blk, blk, 0, stream>>>(h32, batch, gbuf);

    // ---- MLP head (RB=8, unroll 4; 64-thread blocks for wave-granular balance) ----
    dense_t<H, 0, 8><<<((NG / 8) * FFD + 63) / 64, 64, 0, stream>>>(gbuf, W1t, b1, f1, NG, FFD);
    dense_t<FFD, 0, 8><<<((NG / 8) * FFD + 63) / 64, 64, 0, stream>>>(f1, W2t, b2, f2, NG, FFD);
    dense_t<FFD, 0, 8><<<((NG / 8) * FFD + 63) / 64, 64, 0, stream>>>(f2, W3t, b3, f3, NG, FFD);
    dense_t<FFD, 1, 8><<<((NG / 8) * NLB + 63) / 64, 64, 0, stream>>>(f3, Wpt, bp, out, NG, NLB);
}

// Round 22
// 636.888 us; speedup vs baseline: 1.5517x; 1.5517x over previous
//
#include <hip/hip_runtime.h>
#include <math.h>

#define H 43
#define HP 64                     // fp16 row pad -> 128B
#define HR 44                     // f32 h row stride
#define NC 176                    // B cols: 44 f-groups x 4 gates
#define KD 128                    // GEMM K: agg(64) | h(64)
#define NN 100000
#define NE 1600000
#define NG 2048
#define FFD 392
#define NLB 138
#define NXCD 8
#define SHARD 12544               // 128 buckets of 98 nodes
#define GRU_GRID (NXCD * 98)
#define GA_BLOCKS (NXCD * (SHARD / 4))
#define NSB 1024                  // sub-buckets
#define RNG 98                    // dst-nodes per sub-bucket
#define SCAP 2048                 // per-sub-bucket edge capacity (mean 1562)
#define PB 256                    // partition grid
#define PCHUNK ((NE + PB - 1) / PB) // 6250

typedef _Float16 half8 __attribute__((ext_vector_type(8)));
typedef float f32x4 __attribute__((ext_vector_type(4)));

// ---------- partition: edges -> 1024 sub-buckets, packed (src<<7 | d_local) ----------
__global__ void part1024(const int* __restrict__ src, const int* __restrict__ dst,
                         int* __restrict__ scnt, int* __restrict__ ebuf) {
    __shared__ int cnt[NSB];
    __shared__ int base[NSB];
    int e0 = blockIdx.x * PCHUNK, e1 = min(NE, e0 + PCHUNK);
    for (int i = threadIdx.x; i < NSB; i += 256) cnt[i] = 0;
    __syncthreads();
    for (int e = e0 + threadIdx.x; e < e1; e += 256) {
        atomicAdd(&cnt[dst[e] / RNG], 1);
    }
    __syncthreads();
    for (int i = threadIdx.x; i < NSB; i += 256) {
        base[i] = cnt[i] ? atomicAdd(&scnt[i], cnt[i]) : 0;
        cnt[i] = 0;
    }
    __syncthreads();
    for (int e = e0 + threadIdx.x; e < e1; e += 256) {
        int d = dst[e];
        int s = d / RNG;
        int dl = d - s * RNG;
        int off = atomicAdd(&cnt[s], 1);
        int slot = base[s] + off;
        if (slot < SCAP) ebuf[(size_t)s * SCAP + slot] = (src[e] << 7) | dl;
    }
}

// ---------- per-bucket LDS counting sort -> coalesced esorted + rowb/rowe ----------
__global__ __launch_bounds__(256) void sort_sb(const int* __restrict__ ebuf,
                                               const int* __restrict__ scnt,
                                               int* __restrict__ esorted,
                                               int* __restrict__ rowb,
                                               int* __restrict__ rowe) {
    __shared__ int cnt[RNG + 1];
    __shared__ int lpre[RNG + 1];
    __shared__ int inb[SCAP];
    __shared__ int outb[SCAP];
    int b = blockIdx.x;
    int n = min(scnt[b], SCAP);
    const int* buf = ebuf + (size_t)b * SCAP;
    for (int i = threadIdx.x; i < RNG + 1; i += 256) cnt[i] = 0;
    __syncthreads();
    for (int i = threadIdx.x; i < n; i += 256) {
        int p = buf[i];
        inb[i] = p;
        atomicAdd(&cnt[p & 127], 1);
    }
    __syncthreads();
    if (threadIdx.x == 0) {
        int run = 0;
        for (int d = 0; d <= RNG; ++d) { lpre[d] = run; run += cnt[d]; }
    }
    __syncthreads();
    for (int i = threadIdx.x; i < RNG + 1; i += 256) cnt[i] = 0;
    __syncthreads();
    for (int i = threadIdx.x; i < n; i += 256) {
        int p = inb[i];
        int d = p & 127;
        int slot = lpre[d] + atomicAdd(&cnt[d], 1);
        outb[slot] = p >> 7;             // store src only
    }
    __syncthreads();
    for (int i = threadIdx.x; i < n; i += 256)
        esorted[(size_t)b * SCAP + i] = outb[i];   // coalesced
    for (int d = threadIdx.x; d < RNG; d += 256) {
        int node = b * RNG + d;
        if (node < NN) {
            rowb[node] = b * SCAP + lpre[d];
            rowe[node] = b * SCAP + lpre[d + 1];
        }
    }
}

// ---------- Bp: per-layer fused GRU weight matrix, fragment-packed fp16 ----------
__global__ void bp_build(const float* __restrict__ W, const float* __restrict__ W_ih,
                         const float* __restrict__ W_hh, const float* __restrict__ b_ih,
                         const float* __restrict__ b_hh, _Float16* __restrict__ Bp) {
    int t = blockIdx.x * blockDim.x + threadIdx.x;
    if (t >= 5 * KD * NC) return;
    int l = t / (KD * NC);
    int rem = t % (KD * NC);
    int k = rem / NC, c = rem % NC;
    int f = c >> 2, gate = c & 3;
    float v = 0.f;
    if (f < H) {
        if (k < H) {
            if (gate < 3) {
                int col = gate * H + f;
                float acc = 0.f;
#pragma unroll
                for (int c2 = 0; c2 < H; ++c2)
                    acc += W[((size_t)l * H + k) * H + c2] * W_ih[col * H + c2];
                v = acc;
            }
        } else if (k == H) {
            v = (gate == 0) ? b_ih[f] + b_hh[f]
              : (gate == 1) ? b_ih[H + f] + b_hh[H + f]
              : (gate == 2) ? b_ih[2 * H + f]
                            : b_hh[2 * H + f];
        } else if (k >= 64) {
            int k2 = k - 64;
            if (k2 < H) {
                if (gate == 0)      v = W_hh[f * H + k2];
                else if (gate == 1) v = W_hh[(H + f) * H + k2];
                else if (gate == 3) v = W_hh[(2 * H + f) * H + k2];
            }
        }
    }
    int nt = c >> 4, cl = c & 15;
    int kk = k >> 5, r = k & 31;
    int lane = ((r >> 3) << 4) | cl, j = r & 7;
    Bp[(((size_t)l * 11 + nt) * 4 + kk) * 512 + lane * 8 + j] = (_Float16)v;
}

// ---------- generic transpose ----------
__global__ void tr_mat(const float* __restrict__ A, float* __restrict__ At, int R, int C) {
    int t = blockIdx.x * blockDim.x + threadIdx.x;
    if (t >= R * C) return;
    int i = t / C, j = t % C;
    At[(size_t)j * R + i] = A[t];
}

// ---------- seed hh (fp16 rows) and h32 (f32 rows) from x ----------
__global__ void seed_hh(const float* __restrict__ x, _Float16* __restrict__ hh) {
    int t = blockIdx.x * blockDim.x + threadIdx.x;
    if (t >= NN * HP) return;
    int n = t >> 6, f = t & (HP - 1);
    hh[t] = (f < H) ? (_Float16)x[n * H + f] : (_Float16)0.f;
}

__global__ void seed_h32(const float* __restrict__ x, float* __restrict__ h32) {
    int t = blockIdx.x * blockDim.x + threadIdx.x;
    if (t >= NN * HR) return;
    int n = t / HR, f = t % HR;
    h32[t] = (f < H) ? x[n * H + f] : 0.f;
}

// ---------- gather: aggF16[n][f] = sum of hh[src][f]; slot 43=1.0 (bias) ----------
// 16-deep load pipeline.
__global__ __launch_bounds__(256) void gather_t(const _Float16* __restrict__ hh,
                                                const int* __restrict__ rowb,
                                                const int* __restrict__ rowe,
                                                const int* __restrict__ esorted,
                                                _Float16* __restrict__ aggF16) {
    int g = blockIdx.x & (NXCD - 1);
    int i = blockIdx.x >> 3;
    int wid = g * SHARD + i * 4 + (threadIdx.x >> 6);
    int lane = threadIdx.x & 63;
    if (wid >= NN) return;
    int beg = rowb[wid], end = rowe[wid];
    int fc = (lane < H) ? lane : 0;
    float acc = 0.f;
    for (int base = beg; base < end; base += 64) {
        int cnt = min(64, end - base);
        int idx = (base + lane < end) ? esorted[base + lane] : 0;
        int r = 0;
        for (; r + 16 <= cnt; r += 16) {
            int ss[16];
            float vv[16];
#pragma unroll
            for (int q = 0; q < 16; ++q) ss[q] = __shfl(idx, r + q);
#pragma unroll
            for (int q = 0; q < 16; ++q) vv[q] = (float)hh[(size_t)ss[q] * HP + fc];
            float s01 = (vv[0] + vv[1]) + (vv[2] + vv[3]);
            float s23 = (vv[4] + vv[5]) + (vv[6] + vv[7]);
            float s45 = (vv[8] + vv[9]) + (vv[10] + vv[11]);
            float s67 = (vv[12] + vv[13]) + (vv[14] + vv[15]);
            acc += (s01 + s23) + (s45 + s67);
        }
        if (r + 8 <= cnt) {
            int s0 = __shfl(idx, r + 0), s1 = __shfl(idx, r + 1);
            int s2 = __shfl(idx, r + 2), s3 = __shfl(idx, r + 3);
            int s4 = __shfl(idx, r + 4), s5 = __shfl(idx, r + 5);
            int s6 = __shfl(idx, r + 6), s7 = __shfl(idx, r + 7);
            float v0 = (float)hh[(size_t)s0 * HP + fc];
            float v1 = (float)hh[(size_t)s1 * HP + fc];
            float v2 = (float)hh[(size_t)s2 * HP + fc];
            float v3 = (float)hh[(size_t)s3 * HP + fc];
            float v4 = (float)hh[(size_t)s4 * HP + fc];
            float v5 = (float)hh[(size_t)s5 * HP + fc];
            float v6 = (float)hh[(size_t)s6 * HP + fc];
            float v7 = (float)hh[(size_t)s7 * HP + fc];
            acc += ((v0 + v1) + (v2 + v3)) + ((v4 + v5) + (v6 + v7));
            r += 8;
        }
        if (r + 4 <= cnt) {
            int s0 = __shfl(idx, r + 0), s1 = __shfl(idx, r + 1);
            int s2 = __shfl(idx, r + 2), s3 = __shfl(idx, r + 3);
            float v0 = (float)hh[(size_t)s0 * HP + fc];
            float v1 = (float)hh[(size_t)s1 * HP + fc];
            float v2 = (float)hh[(size_t)s2 * HP + fc];
            float v3 = (float)hh[(size_t)s3 * HP + fc];
            acc += (v0 + v1) + (v2 + v3);
            r += 4;
        }
        for (; r < cnt; ++r) {
            int s = __shfl(idx, r);
            acc += (float)hh[(size_t)s * HP + fc];
        }
    }
    _Float16 w = (lane < H) ? (_Float16)acc : (lane == H) ? (_Float16)1.f : (_Float16)0.f;
    aggF16[(size_t)wid * HP + lane] = w;
}

// ---------- GRU via MFMA, barrier-free (double-buffered hh) ----------
__global__ __launch_bounds__(256) void gru_mfma(const _Float16* __restrict__ aggF16,
                                                const _Float16* __restrict__ hh_in,
                                                _Float16* __restrict__ hh_out,
                                                float* __restrict__ h32,
                                                const _Float16* __restrict__ Bp_l) {
    int g = blockIdx.x & (NXCD - 1);
    int blk = blockIdx.x >> 3;
    int lane = threadIdx.x & 63;
    int w = __builtin_amdgcn_readfirstlane(threadIdx.x >> 6);
    int m = lane & 15, kb = lane >> 4;
    int gate = lane & 3;
    int qbase = lane & ~3;

    half8 bf[3][4];
#pragma unroll
    for (int s = 0; s < 3; ++s) {
        int nt = w + s * 4;
        if (nt < 11) {
#pragma unroll
            for (int kk = 0; kk < 4; ++kk)
                bf[s][kk] = *(const half8*)(Bp_l + (((size_t)nt * 4 + kk) * 64 + lane) * 8);
        }
    }

    for (int it = 0; it < 8; ++it) {
        int node0 = g * SHARD + (blk * 8 + it) * 16;
        int ncl = min(node0 + m, NN - 1);
        half8 a0 = *(const half8*)(aggF16 + (size_t)ncl * HP + kb * 8);
        half8 a1 = *(const half8*)(aggF16 + (size_t)ncl * HP + 32 + kb * 8);
        half8 a2 = *(const half8*)(hh_in + (size_t)ncl * HP + kb * 8);
        half8 a3 = *(const half8*)(hh_in + (size_t)ncl * HP + 32 + kb * 8);
#pragma unroll
        for (int s = 0; s < 3; ++s) {
            int nt = w + s * 4;
            if (nt >= 11) continue;
            f32x4 acc = {0.f, 0.f, 0.f, 0.f};
            acc = __builtin_amdgcn_mfma_f32_16x16x32_f16(a0, bf[s][0], acc, 0, 0, 0);
            acc = __builtin_amdgcn_mfma_f32_16x16x32_f16(a1, bf[s][1], acc, 0, 0, 0);
            acc = __builtin_amdgcn_mfma_f32_16x16x32_f16(a2, bf[s][2], acc, 0, 0, 0);
            acc = __builtin_amdgcn_mfma_f32_16x16x32_f16(a3, bf[s][3], acc, 0, 0, 0);
            int f = nt * 4 + ((lane & 15) >> 2);
            float y0 = 0.f, y1 = 0.f, y2 = 0.f, y3 = 0.f;
#pragma unroll
            for (int j = 0; j < 4; ++j) {
                float v = acc[j];
                float x0 = __shfl(v, qbase + 0);
                float x1 = __shfl(v, qbase + 1);
                float x2 = __shfl(v, qbase + 2);
                float x3 = __shfl(v, qbase + 3);
                if (j == gate) { y0 = x0; y1 = x1; y2 = x2; y3 = x3; }
            }
            int node = node0 + (lane >> 4) * 4 + gate;
            if (f < H && node < NN) {
                float r = 1.f / (1.f + __expf(-y0));
                float z = 1.f / (1.f + __expf(-y1));
                float na = y2 + r * y3;
                float e2 = __expf(2.f * na);
                float nv = 1.f - 2.f / (e2 + 1.f);
                float hp = h32[(size_t)node * HR + f];
                float hnew = (1.f - z) * nv + z * hp;
                h32[(size_t)node * HR + f] = hnew;
                hh_out[(size_t)node * HP + f] = (_Float16)hnew;
            }
        }
    }
    for (int i = threadIdx.x; i < 128 * (HP - H); i += 256) {
        int nl = i / (HP - H), f = H + i % (HP - H);
        int node = g * SHARD + blk * 128 + nl;
        if (node < NN) hh_out[(size_t)node * HP + f] = (_Float16)0.f;
    }
}

// ---------- pool over sorted batch ----------
__global__ void pool_r(const float* __restrict__ h32, const int* __restrict__ batch,
                       float* __restrict__ gout) {
    int wid = (blockIdx.x * blockDim.x + threadIdx.x) >> 6;
    int lane = threadIdx.x & 63;
    if (wid >= NG) return;
    int lo = 0, hi = NN;
    while (lo < hi) { int mid = (lo + hi) >> 1; if (batch[mid] < wid) lo = mid + 1; else hi = mid; }
    int beg = lo;
    lo = beg; hi = NN;
    while (lo < hi) { int mid = (lo + hi) >> 1; if (batch[mid] < wid + 1) lo = mid + 1; else hi = mid; }
    int end = lo;
    if (lane < H) {
        float acc = 0.f;
        for (int n = beg; n < end; ++n) acc += h32[(size_t)n * HR + lane];
        gout[wid * H + lane] = acc;
    }
}

// ---------- dense with transposed weights (proven best: unroll 4, RB=8) ----------
template <int K, int ACT, int RB>
__global__ void dense_t(const float* __restrict__ in, const float* __restrict__ Wt,
                        const float* __restrict__ b, float* __restrict__ out,
                        int rows, int cols) {
    int t = blockIdx.x * blockDim.x + threadIdx.x;
    int ngroups = rows / RB;
    if (t >= ngroups * cols) return;
    int c = t % cols;
    int r0 = (t / cols) * RB;
    float acc[RB];
#pragma unroll
    for (int r = 0; r < RB; ++r) acc[r] = b[c];
#pragma unroll 4
    for (int k = 0; k < K; ++k) {
        float w = Wt[(size_t)k * cols + c];
#pragma unroll
        for (int r = 0; r < RB; ++r) acc[r] += in[(r0 + r) * K + k] * w;
    }
#pragma unroll
    for (int r = 0; r < RB; ++r) {
        float v = acc[r];
        v = (ACT == 0) ? fmaxf(v, 0.f) : 1.f / (1.f + expf(-v));
        out[(r0 + r) * cols + c] = v;
    }
}

static inline size_t rnd256(size_t x) { return (x + 255) & ~(size_t)255; }

extern "C" void kernel_launch(void* const* d_in, const int* in_sizes, int n_in,
                              void* d_out, int out_size, void* d_ws, size_t ws_size,
                              hipStream_t stream) {
    const float* x     = (const float*)d_in[0];
    const int*   ei    = (const int*)d_in[1];
    const int*   batch = (const int*)d_in[2];
    const float* W     = (const float*)d_in[3];
    const float* W_ih  = (const float*)d_in[4];
    const float* W_hh  = (const float*)d_in[5];
    const float* b_ih  = (const float*)d_in[6];
    const float* b_hh  = (const float*)d_in[7];
    const float* W1    = (const float*)d_in[8];
    const float* b1    = (const float*)d_in[9];
    const float* W2    = (const float*)d_in[10];
    const float* b2    = (const float*)d_in[11];
    const float* W3    = (const float*)d_in[12];
    const float* b3    = (const float*)d_in[13];
    const float* Wp    = (const float*)d_in[14];
    const float* bp    = (const float*)d_in[15];
    float* out = (float*)d_out;

    const int* src = ei;
    const int* dst = ei + NE;

    char* ws = (char*)d_ws;
    _Float16* aggF16 = (_Float16*)ws; ws += rnd256((size_t)NN * HP * sizeof(_Float16));
    _Float16* hha    = (_Float16*)ws; ws += rnd256((size_t)NN * HP * sizeof(_Float16));
    _Float16* hhb    = (_Float16*)ws; ws += rnd256((size_t)NN * HP * sizeof(_Float16));
    float*    h32    = (float*)ws;    ws += rnd256((size_t)NN * HR * sizeof(float));
    int*   ebuf  = (int*)ws;   ws += rnd256((size_t)NSB * SCAP * sizeof(int));
    int*   esrt  = (int*)ws;   ws += rnd256((size_t)NSB * SCAP * sizeof(int));
    int*   scnt  = (int*)ws;   ws += rnd256((size_t)NSB * sizeof(int));
    int*   rowb  = (int*)ws;   ws += rnd256((size_t)NN * sizeof(int));
    int*   rowe  = (int*)ws;   ws += rnd256((size_t)NN * sizeof(int));
    _Float16* Bp = (_Float16*)ws; ws += rnd256((size_t)5 * 11 * 4 * 512 * sizeof(_Float16));
    float* gbuf  = (float*)ws; ws += rnd256((size_t)NG * H * sizeof(float));
    float* f1    = (float*)ws; ws += rnd256((size_t)NG * FFD * sizeof(float));
    float* f2    = (float*)ws; ws += rnd256((size_t)NG * FFD * sizeof(float));
    float* f3    = (float*)ws; ws += rnd256((size_t)NG * FFD * sizeof(float));
    float* W1t   = (float*)ws; ws += rnd256((size_t)H * FFD * sizeof(float));
    float* W2t   = (float*)ws; ws += rnd256((size_t)FFD * FFD * sizeof(float));
    float* W3t   = (float*)ws; ws += rnd256((size_t)FFD * FFD * sizeof(float));
    float* Wpt   = (float*)ws; ws += rnd256((size_t)FFD * NLB * sizeof(float));

    const int blk = 256;

    // ---- edge prep: bin -> per-bucket LDS sort ----
    hipMemsetAsync(scnt, 0, (size_t)NSB * sizeof(int), stream);
    part1024<<<PB, blk, 0, stream>>>(src, dst, scnt, ebuf);
    sort_sb<<<NSB, blk, 0, stream>>>(ebuf, scnt, esrt, rowb, rowe);

    // ---- weight prep + seed ----
    bp_build<<<(5 * KD * NC + blk - 1) / blk, blk, 0, stream>>>(W, W_ih, W_hh, b_ih, b_hh, Bp);
    seed_hh<<<(NN * HP + blk - 1) / blk, blk, 0, stream>>>(x, hha);
    seed_h32<<<(NN * HR + blk - 1) / blk, blk, 0, stream>>>(x, h32);
    tr_mat<<<(FFD * H + blk - 1) / blk, blk, 0, stream>>>(W1, W1t, FFD, H);
    tr_mat<<<(FFD * FFD + blk - 1) / blk, blk, 0, stream>>>(W2, W2t, FFD, FFD);
    tr_mat<<<(FFD * FFD + blk - 1) / blk, blk, 0, stream>>>(W3, W3t, FFD, FFD);
    tr_mat<<<(NLB * FFD + blk - 1) / blk, blk, 0, stream>>>(Wp, Wpt, NLB, FFD);

    // ---- 5 GGC layers (hh ping-pong) ----
    _Float16* hcur = hha;
    _Float16* hnxt = hhb;
    for (int l = 0; l < 5; ++l) {
        gather_t<<<GA_BLOCKS, blk, 0, stream>>>(hcur, rowb, rowe, esrt, aggF16);
        gru_mfma<<<GRU_GRID, blk, 0, stream>>>(aggF16, hcur, hnxt, h32,
                                               Bp + (size_t)l * 11 * 4 * 512);
        _Float16* t = hcur; hcur = hnxt; hnxt = t;
    }

    // ---- pool ----
    pool_r<<<(NG * 64 + blk - 1) / blk, blk, 0, stream>>>(h32, batch, gbuf);

    // ---- MLP head (proven best: RB=8, unroll 4) ----
    dense_t<H, 0, 8><<<((NG / 8) * FFD + blk - 1) / blk, blk, 0, stream>>>(gbuf, W1t, b1, f1, NG, FFD);
    dense_t<FFD, 0, 8><<<((NG / 8) * FFD + blk - 1) / blk, blk, 0, stream>>>(f1, W2t, b2, f2, NG, FFD);
    dense_t<FFD, 0, 8><<<((NG / 8) * FFD + blk - 1) / blk, blk, 0, stream>>>(f2, W3t, b3, f3, NG, FFD);
    dense_t<FFD, 1, 8><<<((NG / 8) * NLB + blk - 1) / blk, blk, 0, stream>>>(f3, Wpt, bp, out, NG, NLB);
}